// Round 11
// baseline (1063.418 us; speedup 1.0000x reference)
//
#include <hip/hip_runtime.h>

#define N_DIM 256
#define BATCH 64
#define BS 64          // one wave per block; lane t owns columns/rows 4t..4t+3
#define SCALE 4096.0f  // fixed-point scale 2^12

#define DPP_MINU(x, ctrl) do {                                                 \
    unsigned _s = (unsigned)__builtin_amdgcn_update_dpp((int)(x), (int)(x),    \
                                                        (ctrl), 0xf, 0xf, false); \
    (x) = ((x) < _s) ? (x) : _s;                                               \
} while (0)

// Hybrid full-wave u32 min: 4 DPP stages reduce within each 16-lane row
// (result in lanes 15/31/47/63), then 4 independent readlanes + scalar mins.
__device__ __forceinline__ unsigned wave_min_u32(unsigned x) {
    DPP_MINU(x, 0x111);  // row_shr:1
    DPP_MINU(x, 0x112);  // row_shr:2
    DPP_MINU(x, 0x114);  // row_shr:4
    DPP_MINU(x, 0x118);  // row_shr:8
    const unsigned a = (unsigned)__builtin_amdgcn_readlane((int)x, 15);
    const unsigned b = (unsigned)__builtin_amdgcn_readlane((int)x, 31);
    const unsigned c = (unsigned)__builtin_amdgcn_readlane((int)x, 47);
    const unsigned d = (unsigned)__builtin_amdgcn_readlane((int)x, 63);
    const unsigned ab = (a < b) ? a : b;
    const unsigned cd = (c < d) ? c : d;
    return (ab < cd) ? ab : cd;
}

// uniform-index lookup from 4 per-lane mirror regs: 2 selects + 1 readlane
__device__ __forceinline__ int rd4_i(int x0, int x1, int x2, int x3, int idx) {
    const int sel = idx & 3, src = idx >> 2;
    int ab = (sel & 1) ? x1 : x0;
    int cd = (sel & 1) ? x3 : x2;
    int vv = (sel & 2) ? cd : ab;
    return __builtin_amdgcn_readlane(vv, src);
}

// owner-lane mirror update (idx wave-uniform)
#define SET4(x0, x1, x2, x3, idx, val) do {                                    \
    const int _sel = (idx) & 3;                                                \
    if (t == ((idx) >> 2)) {                                                   \
        if (_sel == 0) x0 = (val); else if (_sel == 1) x1 = (val);             \
        else if (_sel == 2) x2 = (val); else x3 = (val);                       \
    }                                                                          \
} while (0)

__device__ __forceinline__ int lo16(int p) { return (int)(short)(p & 0xFFFF); }
__device__ __forceinline__ int hi16(int p) { return p >> 16; }

// One block = one wave = one batch element.
// JV/auction LAP in i32 FIXED-POINT (scale 2^12) on i16-packed costs in LDS:
//   1) column reduction + greedy init
//   2) lane-parallel epsilon=1 auction. FIXES vs R9: bids cleared at the start
//      of EVERY pass (stale losing bids were permanently ghost-blocking
//      columns), and displaced rows get u reset to 0 (stale u could exceed
//      the current best reduced cost -> negative keys in Dijkstra).
//   3) shortest augmenting path (Dijkstra) fallback for leftover rows --
//      exact for feasible duals; total epsilon-CS slack <= n units = 2.4e-4
//      on the final mean (threshold 5.4e-2). Final gather uses ORIGINAL f32.
__global__ __launch_bounds__(BS) void lap_kernel(const float* __restrict__ Dm,
                                                 double* __restrict__ batch_sums) {
    const int b = blockIdx.x;
    const int t = threadIdx.x;  // 0..63
    const float* __restrict__ cost = Dm + (size_t)b * N_DIM * N_DIM;
    const float4* __restrict__ cost4 = (const float4*)cost;

    __shared__ int2     chi[N_DIM * BS];    // [row][lane]: 4 i16 costs, 128 KB
    __shared__ int      u_s[N_DIM];
    __shared__ int      v_s[N_DIM];
    __shared__ int      row4col_s[N_DIM];
    __shared__ int      col4row_s[N_DIM];
    __shared__ int      queue_s[N_DIM];     // doubles as rowcand during greedy
    __shared__ unsigned bid_s[N_DIM];
    __shared__ int      qcnt_s;

    const int c0i = 4 * t, c1i = 4 * t + 1, c2i = 4 * t + 2, c3i = 4 * t + 3;

    // ---- stage i16 matrix + column reduction on QUANTIZED values ----
    int cmn0 = INT_MAX, cmn1 = INT_MAX, cmn2 = INT_MAX, cmn3 = INT_MAX;
    int ca0 = 0, ca1 = 0, ca2 = 0, ca3 = 0;
    for (int r = 0; r < N_DIM; ++r) {
        const float4 c4 = cost4[r * BS + t];
        const int a0 = __float2int_rn(c4.x * SCALE);
        const int a1 = __float2int_rn(c4.y * SCALE);
        const int a2 = __float2int_rn(c4.z * SCALE);
        const int a3 = __float2int_rn(c4.w * SCALE);
        int2 p;
        p.x = (a0 & 0xFFFF) | (a1 << 16);
        p.y = (a2 & 0xFFFF) | (a3 << 16);
        chi[r * BS + t] = p;
        if (a0 < cmn0) { cmn0 = a0; ca0 = r; }
        if (a1 < cmn1) { cmn1 = a1; ca1 = r; }
        if (a2 < cmn2) { cmn2 = a2; ca2 = r; }
        if (a3 < cmn3) { cmn3 = a3; ca3 = r; }
    }
    {
        int4 vv; vv.x = cmn0; vv.y = cmn1; vv.z = cmn2; vv.w = cmn3;
        ((int4*)v_s)[t] = vv;
        int4 zz; zz.x = 0; zz.y = 0; zz.z = 0; zz.w = 0;
        ((int4*)u_s)[t] = zz;
        int4 mm; mm.x = -1; mm.y = -1; mm.z = -1; mm.w = -1;
        ((int4*)row4col_s)[t] = mm;
        ((int4*)col4row_s)[t] = mm;
        int4 rc; rc.x = 0x7fffffff; rc.y = 0x7fffffff; rc.z = 0x7fffffff; rc.w = 0x7fffffff;
        ((int4*)queue_s)[t] = rc;   // rowcand
        uint4 bb; bb.x = ~0u; bb.y = ~0u; bb.z = ~0u; bb.w = ~0u;
        ((uint4*)bid_s)[t] = bb;
    }
    __syncthreads();
    // greedy: each candidate row goes to the lowest claiming column
    atomicMin(&queue_s[ca0], c0i);
    atomicMin(&queue_s[ca1], c1i);
    atomicMin(&queue_s[ca2], c2i);
    atomicMin(&queue_s[ca3], c3i);
    __syncthreads();
    if (queue_s[ca0] == c0i) { row4col_s[c0i] = ca0; col4row_s[ca0] = c0i; }
    if (queue_s[ca1] == c1i) { row4col_s[c1i] = ca1; col4row_s[ca1] = c1i; }
    if (queue_s[ca2] == c2i) { row4col_s[c2i] = ca2; col4row_s[ca2] = c2i; }
    if (queue_s[ca3] == c3i) { row4col_s[c3i] = ca3; col4row_s[ca3] = c3i; }
    __syncthreads();

    // ---- lane-parallel epsilon=1 auction (bids cleared every pass) ----
    for (int pass = 0; pass < 96; ++pass) {
        if (t == 0) qcnt_s = 0;
        __syncthreads();
        {
            // clear my 4 columns' bids: stale losing bids from the previous
            // pass must not ghost-block this pass (prices only fall, so a
            // lingering old bid is unbeatable).
            uint4 bb; bb.x = ~0u; bb.y = ~0u; bb.z = ~0u; bb.w = ~0u;
            ((uint4*)bid_s)[t] = bb;
            const int4 my = ((const int4*)col4row_s)[t];
            const int nf = (my.x < 0) + (my.y < 0) + (my.z < 0) + (my.w < 0);
            if (nf) {
                int pos = atomicAdd(&qcnt_s, nf);
                if (my.x < 0) queue_s[pos++] = c0i;
                if (my.y < 0) queue_s[pos++] = c1i;
                if (my.z < 0) queue_s[pos++] = c2i;
                if (my.w < 0) queue_s[pos++] = c3i;
            }
        }
        __syncthreads();
        const int n = qcnt_s;
        if (n == 0) break;
        for (int base = 0; base < n; base += BS) {
            const int my_row = (base + t < n) ? queue_s[base + t] : -1;
            int d1 = INT_MAX, d2 = INT_MAX;
            int j1 = 0;
            if (my_row >= 0) {
                const int rb = my_row * BS;
                for (int l = 0; l < BS; ++l) {
                    const int l2 = (l + t) & 63;  // rotate start: avoid bank pileup
                    const int2 h = chi[rb + l2];
                    const int4 vv = ((const int4*)v_s)[l2];
                    int d;
                    d = lo16(h.x) - vv.x; if (d < d1) { d2 = d1; d1 = d; j1 = 4 * l2 + 0; } else if (d < d2) d2 = d;
                    d = hi16(h.x) - vv.y; if (d < d1) { d2 = d1; d1 = d; j1 = 4 * l2 + 1; } else if (d < d2) d2 = d;
                    d = lo16(h.y) - vv.z; if (d < d1) { d2 = d1; d1 = d; j1 = 4 * l2 + 2; } else if (d < d2) d2 = d;
                    d = hi16(h.y) - vv.w; if (d < d1) { d2 = d1; d1 = d; j1 = 4 * l2 + 3; } else if (d < d2) d2 = d;
                }
                atomicMin(&bid_s[j1], ((unsigned)d1 << 8) | (unsigned)t);
            }
            __syncthreads();
            if (my_row >= 0) {
                const unsigned mybid = ((unsigned)d1 << 8) | (unsigned)t;
                if (bid_s[j1] == mybid) {  // unique winner per column
                    const int i0 = row4col_s[j1];
                    row4col_s[j1] = my_row;
                    col4row_s[my_row] = j1;
                    if (i0 >= 0) {
                        col4row_s[i0] = -1;
                        u_s[i0] = 0;       // stale u may exceed current best
                    }
                    u_s[my_row] = d2;
                    // epsilon=1: strict price decrease -> ties make progress;
                    // winner's slack vs its best is exactly 1 unit (feasible).
                    v_s[j1] += d1 - d2 - 1;
                }
            }
            __syncthreads();
        }
    }

    // ---- refresh register state from LDS ----
    const int4 vv4 = ((const int4*)v_s)[t];
    int vn0 = -vv4.x, vn1 = -vv4.y, vn2 = -vv4.z, vn3 = -vv4.w;  // negated duals
    const int4 m4 = ((const int4*)row4col_s)[t];
    int r4c0 = m4.x, r4c1 = m4.y, r4c2 = m4.z, r4c3 = m4.w;
    const int4 y4 = ((const int4*)col4row_s)[t];
    int c4r0 = y4.x, c4r1 = y4.y, c4r2 = y4.z, c4r3 = y4.w;
    int p0 = 0, p1 = 0, p2 = 0, p3 = 0;

    unsigned long long fm0 = __ballot(c4r0 < 0);
    unsigned long long fm1 = __ballot(c4r1 < 0);
    unsigned long long fm2 = __ballot(c4r2 < 0);
    unsigned long long fm3 = __ballot(c4r3 < 0);

    const int KINIT0 = (0x7FFFFF << 8) | c0i;
    const int KINIT1 = (0x7FFFFF << 8) | c1i;
    const int KINIT2 = (0x7FFFFF << 8) | c2i;
    const int KINIT3 = (0x7FFFFF << 8) | c3i;

    // ---- shortest augmenting path per remaining free row ----
    while (fm0 | fm1 | fm2 | fm3) {
        int i;
        if (fm0)      { const int tt = __builtin_ctzll(fm0); fm0 &= fm0 - 1; i = tt * 4 + 0; }
        else if (fm1) { const int tt = __builtin_ctzll(fm1); fm1 &= fm1 - 1; i = tt * 4 + 1; }
        else if (fm2) { const int tt = __builtin_ctzll(fm2); fm2 &= fm2 - 1; i = tt * 4 + 2; }
        else          { const int tt = __builtin_ctzll(fm3); fm3 &= fm3 - 1; i = tt * 4 + 3; }

        int k0 = KINIT0, k1 = KINIT1, k2 = KINIT2, k3 = KINIT3;  // (spc<<8)|col
        int g0 = 0, g1 = 0, g2 = 0, g3 = 0;                      // scan guards
        int cur = i;
        int minVal = 0;
        int sink = -1;

        while (true) {
            const int2 h   = chi[cur * BS + t];   // ds_read_b64
            const int ucur = u_s[cur];            // uniform LDS read (parallel)
            const int add  = minVal - ucur;

            // integer relax; monotone for scanned cols (r >= minVal >= spc)
            int r, kn;
            r  = add + lo16(h.x) + vn0;
            kn = (r << 8) | c0i; if (kn < k0) { p0 = cur; k0 = kn; }
            r  = add + hi16(h.x) + vn1;
            kn = (r << 8) | c1i; if (kn < k1) { p1 = cur; k1 = kn; }
            r  = add + lo16(h.y) + vn2;
            kn = (r << 8) | c2i; if (kn < k2) { p2 = cur; k2 = kn; }
            r  = add + hi16(h.y) + vn3;
            kn = (r << 8) | c3i; if (kn < k3) { p3 = cur; k3 = kn; }

            // guarded argmin (scanned cols masked to INT_MAX via OR)
            const int q0 = k0 | g0, q1 = k1 | g1, q2 = k2 | g2, q3 = k3 | g3;
            int q01 = (q0 < q1) ? q0 : q1;
            int q23 = (q2 < q3) ? q2 : q3;
            const int gk = (int)wave_min_u32((unsigned)((q01 < q23) ? q01 : q23));

            const int bi = gk & 0xFF;
            minVal = gk >> 8;                                   // exact spc of pop
            const int r4 = rd4_i(r4c0, r4c1, r4c2, r4c3, bi);   // matched row
            if (t == (bi >> 2)) {
                const int s = bi & 3;
                if (s == 0) g0 = 0x7FFFFFFF; else if (s == 1) g1 = 0x7FFFFFFF;
                else if (s == 2) g2 = 0x7FFFFFFF; else g3 = 0x7FFFFFFF;
            }
            if (r4 < 0) { sink = bi; break; }
            cur = r4;
        }

        // dual update (guards mark scanned; matched rows distinct across cols)
        if (g0) { const int dv = minVal - (k0 >> 8); vn0 += dv; if (r4c0 >= 0) u_s[r4c0] += dv; }
        if (g1) { const int dv = minVal - (k1 >> 8); vn1 += dv; if (r4c1 >= 0) u_s[r4c1] += dv; }
        if (g2) { const int dv = minVal - (k2 >> 8); vn2 += dv; if (r4c2 >= 0) u_s[r4c2] += dv; }
        if (g3) { const int dv = minVal - (k3 >> 8); vn3 += dv; if (r4c3 >= 0) u_s[r4c3] += dv; }
        if (t == 0) u_s[i] += minVal;

        // augment alternating path (uniform walk over register mirrors)
        if (sink >= 0) {
            int jj = sink;
            while (true) {
                const int ii = rd4_i(p0, p1, p2, p3, jj);
                SET4(r4c0, r4c1, r4c2, r4c3, jj, ii);
                const int tmp = rd4_i(c4r0, c4r1, c4r2, c4r3, ii);
                SET4(c4r0, c4r1, c4r2, c4r3, ii, jj);
                jj = tmp;
                if (ii == i) break;
            }
        }
    }

    // ---- gather matched ORIGINAL f32 costs (4 rows per lane), reduce in f64 ----
    double s = 0.0;
    s += (double)cost[(size_t)(t * 4 + 0) * N_DIM + c4r0];
    s += (double)cost[(size_t)(t * 4 + 1) * N_DIM + c4r1];
    s += (double)cost[(size_t)(t * 4 + 2) * N_DIM + c4r2];
    s += (double)cost[(size_t)(t * 4 + 3) * N_DIM + c4r3];
    #pragma unroll
    for (int off = 32; off > 0; off >>= 1) s += __shfl_down(s, off);
    if (t == 0) batch_sums[b] = s;
}

__global__ void finalize_kernel(const double* __restrict__ batch_sums,
                                float* __restrict__ out) {
    const int t = threadIdx.x;  // 64 threads, one wave
    double s = batch_sums[t];
    #pragma unroll
    for (int off = 32; off > 0; off >>= 1) s += __shfl_down(s, off);
    if (t == 0) out[0] = (float)(s / (double)((long long)BATCH * N_DIM));
}

extern "C" void kernel_launch(void* const* d_in, const int* in_sizes, int n_in,
                              void* d_out, int out_size, void* d_ws, size_t ws_size,
                              hipStream_t stream) {
    const float* Dm = (const float*)d_in[0];
    float* out = (float*)d_out;
    double* sums = (double*)d_ws;  // 64 * 8 = 512 bytes

    lap_kernel<<<BATCH, BS, 0, stream>>>(Dm, sums);
    finalize_kernel<<<1, 64, 0, stream>>>(sums, out);
}

// Round 12
// 988.288 us; speedup vs baseline: 1.0760x; 1.0760x over previous
//
#include <hip/hip_runtime.h>

#define N_DIM 256
#define BATCH 64
#define BS 64          // one wave per block; lane t owns columns/rows 4t..4t+3
#define SCALE 4096.0f  // fixed-point scale 2^12
#define NPHASE 5

#define DPP_MINU(x, ctrl) do {                                                 \
    unsigned _s = (unsigned)__builtin_amdgcn_update_dpp((int)(x), (int)(x),    \
                                                        (ctrl), 0xf, 0xf, false); \
    (x) = ((x) < _s) ? (x) : _s;                                               \
} while (0)

// Hybrid full-wave u32 min: 4 DPP stages reduce within each 16-lane row
// (result in lanes 15/31/47/63), then 4 independent readlanes + scalar mins.
__device__ __forceinline__ unsigned wave_min_u32(unsigned x) {
    DPP_MINU(x, 0x111);  // row_shr:1
    DPP_MINU(x, 0x112);  // row_shr:2
    DPP_MINU(x, 0x114);  // row_shr:4
    DPP_MINU(x, 0x118);  // row_shr:8
    const unsigned a = (unsigned)__builtin_amdgcn_readlane((int)x, 15);
    const unsigned b = (unsigned)__builtin_amdgcn_readlane((int)x, 31);
    const unsigned c = (unsigned)__builtin_amdgcn_readlane((int)x, 47);
    const unsigned d = (unsigned)__builtin_amdgcn_readlane((int)x, 63);
    const unsigned ab = (a < b) ? a : b;
    const unsigned cd = (c < d) ? c : d;
    return (ab < cd) ? ab : cd;
}

// uniform-index lookup from 4 per-lane mirror regs: 2 selects + 1 readlane
__device__ __forceinline__ int rd4_i(int x0, int x1, int x2, int x3, int idx) {
    const int sel = idx & 3, src = idx >> 2;
    int ab = (sel & 1) ? x1 : x0;
    int cd = (sel & 1) ? x3 : x2;
    int vv = (sel & 2) ? cd : ab;
    return __builtin_amdgcn_readlane(vv, src);
}

// owner-lane mirror update (idx wave-uniform)
#define SET4(x0, x1, x2, x3, idx, val) do {                                    \
    const int _sel = (idx) & 3;                                                \
    if (t == ((idx) >> 2)) {                                                   \
        if (_sel == 0) x0 = (val); else if (_sel == 1) x1 = (val);             \
        else if (_sel == 2) x2 = (val); else x3 = (val);                       \
    }                                                                          \
} while (0)

__device__ __forceinline__ int lo16(int p) { return (int)(short)(p & 0xFFFF); }
__device__ __forceinline__ int hi16(int p) { return p >> 16; }

// cost(row, col) from packed LDS, col arbitrary
__device__ __forceinline__ int chi_at(const int2* chi, int row, int col) {
    const int2 w = chi[row * BS + (col >> 2)];
    const int word = (col & 2) ? w.y : w.x;
    return (col & 1) ? hi16(word) : lo16(word);
}

// One block = one wave = one batch element.
// LAP in i32 fixed-point (scale 2^12), i16-packed costs in LDS:
//   1) column reduction (v=colmin) + greedy init
//   2) EPSILON-SCALING auction (eps 2048->1, /8): bids cleared every pass;
//      prices only fall => kept matches' slack only shrinks (eps-CS stable).
//      Between phases, unmatch only rows violating the NEXT eps (row-min scan).
//      u is never touched by the auction.
//   3) final tighten: u_i = row min (feasible by construction), unmatch any
//      non-tight matched row.
//   4) exact Dijkstra (R8 structure, unchanged) on the few leftover rows.
// Result: exact optimum of the quantized matrix. Gather uses ORIGINAL f32.
__global__ __launch_bounds__(BS) void lap_kernel(const float* __restrict__ Dm,
                                                 double* __restrict__ batch_sums) {
    const int b = blockIdx.x;
    const int t = threadIdx.x;  // 0..63
    const float* __restrict__ cost = Dm + (size_t)b * N_DIM * N_DIM;
    const float4* __restrict__ cost4 = (const float4*)cost;

    __shared__ int2     chi[N_DIM * BS];    // [row][lane]: 4 i16 costs, 128 KB
    __shared__ int      u_s[N_DIM];
    __shared__ int      v_s[N_DIM];
    __shared__ int      row4col_s[N_DIM];
    __shared__ int      col4row_s[N_DIM];
    __shared__ int      queue_s[N_DIM];     // doubles as rowcand during greedy
    __shared__ unsigned bid_s[N_DIM];
    __shared__ int      qcnt_s;

    const int c0i = 4 * t, c1i = 4 * t + 1, c2i = 4 * t + 2, c3i = 4 * t + 3;

    // ---- stage i16 matrix + column reduction on QUANTIZED values ----
    int cmn0 = INT_MAX, cmn1 = INT_MAX, cmn2 = INT_MAX, cmn3 = INT_MAX;
    int ca0 = 0, ca1 = 0, ca2 = 0, ca3 = 0;
    for (int r = 0; r < N_DIM; ++r) {
        const float4 c4 = cost4[r * BS + t];
        const int a0 = __float2int_rn(c4.x * SCALE);
        const int a1 = __float2int_rn(c4.y * SCALE);
        const int a2 = __float2int_rn(c4.z * SCALE);
        const int a3 = __float2int_rn(c4.w * SCALE);
        int2 p;
        p.x = (a0 & 0xFFFF) | (a1 << 16);
        p.y = (a2 & 0xFFFF) | (a3 << 16);
        chi[r * BS + t] = p;
        if (a0 < cmn0) { cmn0 = a0; ca0 = r; }
        if (a1 < cmn1) { cmn1 = a1; ca1 = r; }
        if (a2 < cmn2) { cmn2 = a2; ca2 = r; }
        if (a3 < cmn3) { cmn3 = a3; ca3 = r; }
    }
    {
        int4 vv; vv.x = cmn0; vv.y = cmn1; vv.z = cmn2; vv.w = cmn3;
        ((int4*)v_s)[t] = vv;
        int4 zz; zz.x = 0; zz.y = 0; zz.z = 0; zz.w = 0;
        ((int4*)u_s)[t] = zz;
        int4 mm; mm.x = -1; mm.y = -1; mm.z = -1; mm.w = -1;
        ((int4*)row4col_s)[t] = mm;
        ((int4*)col4row_s)[t] = mm;
        int4 rc; rc.x = 0x7fffffff; rc.y = 0x7fffffff; rc.z = 0x7fffffff; rc.w = 0x7fffffff;
        ((int4*)queue_s)[t] = rc;   // rowcand
    }
    __syncthreads();
    // greedy: each candidate row goes to the lowest claiming column (tight)
    atomicMin(&queue_s[ca0], c0i);
    atomicMin(&queue_s[ca1], c1i);
    atomicMin(&queue_s[ca2], c2i);
    atomicMin(&queue_s[ca3], c3i);
    __syncthreads();
    if (queue_s[ca0] == c0i) { row4col_s[c0i] = ca0; col4row_s[ca0] = c0i; }
    if (queue_s[ca1] == c1i) { row4col_s[c1i] = ca1; col4row_s[ca1] = c1i; }
    if (queue_s[ca2] == c2i) { row4col_s[c2i] = ca2; col4row_s[ca2] = c2i; }
    if (queue_s[ca3] == c3i) { row4col_s[c3i] = ca3; col4row_s[ca3] = c3i; }
    __syncthreads();

    // ---- epsilon-scaling auction ----
    const int eps_tab[NPHASE] = {2048, 256, 32, 4, 1};
    const int cap_tab[NPHASE] = {10, 10, 12, 14, 18};
    for (int ph = 0; ph < NPHASE; ++ph) {
        const int eps = eps_tab[ph];
        for (int pass = 0; pass < cap_tab[ph]; ++pass) {
            if (t == 0) qcnt_s = 0;
            __syncthreads();
            {
                // clear my 4 columns' bids (stale bids would ghost-block)
                uint4 bb; bb.x = ~0u; bb.y = ~0u; bb.z = ~0u; bb.w = ~0u;
                ((uint4*)bid_s)[t] = bb;
                const int4 my = ((const int4*)col4row_s)[t];
                const int nf = (my.x < 0) + (my.y < 0) + (my.z < 0) + (my.w < 0);
                if (nf) {
                    int pos = atomicAdd(&qcnt_s, nf);
                    if (my.x < 0) queue_s[pos++] = c0i;
                    if (my.y < 0) queue_s[pos++] = c1i;
                    if (my.z < 0) queue_s[pos++] = c2i;
                    if (my.w < 0) queue_s[pos++] = c3i;
                }
            }
            __syncthreads();
            const int n = qcnt_s;
            if (n == 0) break;
            for (int base = 0; base < n; base += BS) {
                const int my_row = (base + t < n) ? queue_s[base + t] : -1;
                int d1 = INT_MAX, d2 = INT_MAX;
                int j1 = 0;
                if (my_row >= 0) {
                    const int rb = my_row * BS;
                    for (int l = 0; l < BS; ++l) {
                        const int l2 = (l + t) & 63;  // rotate: avoid bank pileup
                        const int2 h = chi[rb + l2];
                        const int4 vv = ((const int4*)v_s)[l2];
                        int d;
                        d = lo16(h.x) - vv.x; if (d < d1) { d2 = d1; d1 = d; j1 = 4 * l2 + 0; } else if (d < d2) d2 = d;
                        d = hi16(h.x) - vv.y; if (d < d1) { d2 = d1; d1 = d; j1 = 4 * l2 + 1; } else if (d < d2) d2 = d;
                        d = lo16(h.y) - vv.z; if (d < d1) { d2 = d1; d1 = d; j1 = 4 * l2 + 2; } else if (d < d2) d2 = d;
                        d = hi16(h.y) - vv.w; if (d < d1) { d2 = d1; d1 = d; j1 = 4 * l2 + 3; } else if (d < d2) d2 = d;
                    }
                    atomicMin(&bid_s[j1], ((unsigned)d1 << 8) | (unsigned)t);
                }
                __syncthreads();
                if (my_row >= 0) {
                    const unsigned mybid = ((unsigned)d1 << 8) | (unsigned)t;
                    if (bid_s[j1] == mybid) {  // unique winner per column
                        const int i0 = row4col_s[j1];
                        row4col_s[j1] = my_row;
                        col4row_s[my_row] = j1;
                        if (i0 >= 0) col4row_s[i0] = -1;
                        // price strictly falls by >= eps -> finite convergence;
                        // all reduced costs only increase -> duals stay feasible
                        v_s[j1] += d1 - d2 - eps;
                    }
                }
                __syncthreads();
            }
        }

        // ---- phase transition / final tighten ----
        // row-min scan for my 4 rows (under current prices)
        int m0 = INT_MAX, m1 = INT_MAX, m2 = INT_MAX, m3 = INT_MAX;
        for (int l = 0; l < BS; ++l) {
            const int l2 = (l + t) & 63;
            const int4 vv = ((const int4*)v_s)[l2];
            const int2 h0 = chi[c0i * BS + l2];
            const int2 h1 = chi[c1i * BS + l2];
            const int2 h2 = chi[c2i * BS + l2];
            const int2 h3 = chi[c3i * BS + l2];
            int d;
            d = lo16(h0.x) - vv.x; if (d < m0) m0 = d;
            d = hi16(h0.x) - vv.y; if (d < m0) m0 = d;
            d = lo16(h0.y) - vv.z; if (d < m0) m0 = d;
            d = hi16(h0.y) - vv.w; if (d < m0) m0 = d;
            d = lo16(h1.x) - vv.x; if (d < m1) m1 = d;
            d = hi16(h1.x) - vv.y; if (d < m1) m1 = d;
            d = lo16(h1.y) - vv.z; if (d < m1) m1 = d;
            d = hi16(h1.y) - vv.w; if (d < m1) m1 = d;
            d = lo16(h2.x) - vv.x; if (d < m2) m2 = d;
            d = hi16(h2.x) - vv.y; if (d < m2) m2 = d;
            d = lo16(h2.y) - vv.z; if (d < m2) m2 = d;
            d = hi16(h2.y) - vv.w; if (d < m2) m2 = d;
            d = lo16(h3.x) - vv.x; if (d < m3) m3 = d;
            d = hi16(h3.x) - vv.y; if (d < m3) m3 = d;
            d = lo16(h3.y) - vv.z; if (d < m3) m3 = d;
            d = hi16(h3.y) - vv.w; if (d < m3) m3 = d;
        }
        const bool last = (ph == NPHASE - 1);
        const int thr = last ? 0 : eps_tab[ph + 1];
        const int4 my = ((const int4*)col4row_s)[t];
        // unmatch rows whose matched slack exceeds the next-phase tolerance
        if (my.x >= 0 && chi_at(chi, c0i, my.x) - v_s[my.x] - m0 > thr) { col4row_s[c0i] = -1; row4col_s[my.x] = -1; }
        if (my.y >= 0 && chi_at(chi, c1i, my.y) - v_s[my.y] - m1 > thr) { col4row_s[c1i] = -1; row4col_s[my.y] = -1; }
        if (my.z >= 0 && chi_at(chi, c2i, my.z) - v_s[my.z] - m2 > thr) { col4row_s[c2i] = -1; row4col_s[my.z] = -1; }
        if (my.w >= 0 && chi_at(chi, c3i, my.w) - v_s[my.w] - m3 > thr) { col4row_s[c3i] = -1; row4col_s[my.w] = -1; }
        if (last) {
            // u = row min: feasible for any v, tight for every kept match
            int4 uu; uu.x = m0; uu.y = m1; uu.z = m2; uu.w = m3;
            ((int4*)u_s)[t] = uu;
        }
        __syncthreads();
    }

    // ---- refresh register state from LDS ----
    const int4 vv4 = ((const int4*)v_s)[t];
    int vn0 = -vv4.x, vn1 = -vv4.y, vn2 = -vv4.z, vn3 = -vv4.w;  // negated duals
    const int4 m4 = ((const int4*)row4col_s)[t];
    int r4c0 = m4.x, r4c1 = m4.y, r4c2 = m4.z, r4c3 = m4.w;
    const int4 y4 = ((const int4*)col4row_s)[t];
    int c4r0 = y4.x, c4r1 = y4.y, c4r2 = y4.z, c4r3 = y4.w;
    int p0 = 0, p1 = 0, p2 = 0, p3 = 0;

    unsigned long long fm0 = __ballot(c4r0 < 0);
    unsigned long long fm1 = __ballot(c4r1 < 0);
    unsigned long long fm2 = __ballot(c4r2 < 0);
    unsigned long long fm3 = __ballot(c4r3 < 0);

    const int KINIT0 = (0x7FFFFF << 8) | c0i;
    const int KINIT1 = (0x7FFFFF << 8) | c1i;
    const int KINIT2 = (0x7FFFFF << 8) | c2i;
    const int KINIT3 = (0x7FFFFF << 8) | c3i;

    // ---- exact shortest augmenting path per remaining free row (R8) ----
    while (fm0 | fm1 | fm2 | fm3) {
        int i;
        if (fm0)      { const int tt = __builtin_ctzll(fm0); fm0 &= fm0 - 1; i = tt * 4 + 0; }
        else if (fm1) { const int tt = __builtin_ctzll(fm1); fm1 &= fm1 - 1; i = tt * 4 + 1; }
        else if (fm2) { const int tt = __builtin_ctzll(fm2); fm2 &= fm2 - 1; i = tt * 4 + 2; }
        else          { const int tt = __builtin_ctzll(fm3); fm3 &= fm3 - 1; i = tt * 4 + 3; }

        int k0 = KINIT0, k1 = KINIT1, k2 = KINIT2, k3 = KINIT3;  // (spc<<8)|col
        int g0 = 0, g1 = 0, g2 = 0, g3 = 0;                      // scan guards
        int cur = i;
        int minVal = 0;
        int sink = -1;

        while (true) {
            const int2 h   = chi[cur * BS + t];   // ds_read_b64
            const int ucur = u_s[cur];            // uniform LDS read (parallel)
            const int add  = minVal - ucur;

            // integer relax; monotone for scanned cols (r >= minVal >= spc)
            int r, kn;
            r  = add + lo16(h.x) + vn0;
            kn = (r << 8) | c0i; if (kn < k0) { p0 = cur; k0 = kn; }
            r  = add + hi16(h.x) + vn1;
            kn = (r << 8) | c1i; if (kn < k1) { p1 = cur; k1 = kn; }
            r  = add + lo16(h.y) + vn2;
            kn = (r << 8) | c2i; if (kn < k2) { p2 = cur; k2 = kn; }
            r  = add + hi16(h.y) + vn3;
            kn = (r << 8) | c3i; if (kn < k3) { p3 = cur; k3 = kn; }

            // guarded argmin (scanned cols masked to INT_MAX via OR)
            const int q0 = k0 | g0, q1 = k1 | g1, q2 = k2 | g2, q3 = k3 | g3;
            int q01 = (q0 < q1) ? q0 : q1;
            int q23 = (q2 < q3) ? q2 : q3;
            const int gk = (int)wave_min_u32((unsigned)((q01 < q23) ? q01 : q23));

            const int bi = gk & 0xFF;
            minVal = gk >> 8;                                   // exact spc of pop
            const int r4 = rd4_i(r4c0, r4c1, r4c2, r4c3, bi);   // matched row
            if (t == (bi >> 2)) {
                const int s = bi & 3;
                if (s == 0) g0 = 0x7FFFFFFF; else if (s == 1) g1 = 0x7FFFFFFF;
                else if (s == 2) g2 = 0x7FFFFFFF; else g3 = 0x7FFFFFFF;
            }
            if (r4 < 0) { sink = bi; break; }
            cur = r4;
        }

        // dual update (guards mark scanned; matched rows distinct across cols)
        if (g0) { const int dv = minVal - (k0 >> 8); vn0 += dv; if (r4c0 >= 0) u_s[r4c0] += dv; }
        if (g1) { const int dv = minVal - (k1 >> 8); vn1 += dv; if (r4c1 >= 0) u_s[r4c1] += dv; }
        if (g2) { const int dv = minVal - (k2 >> 8); vn2 += dv; if (r4c2 >= 0) u_s[r4c2] += dv; }
        if (g3) { const int dv = minVal - (k3 >> 8); vn3 += dv; if (r4c3 >= 0) u_s[r4c3] += dv; }
        if (t == 0) u_s[i] += minVal;

        // augment alternating path (uniform walk over register mirrors)
        if (sink >= 0) {
            int jj = sink;
            while (true) {
                const int ii = rd4_i(p0, p1, p2, p3, jj);
                SET4(r4c0, r4c1, r4c2, r4c3, jj, ii);
                const int tmp = rd4_i(c4r0, c4r1, c4r2, c4r3, ii);
                SET4(c4r0, c4r1, c4r2, c4r3, ii, jj);
                jj = tmp;
                if (ii == i) break;
            }
        }
    }

    // ---- gather matched ORIGINAL f32 costs (4 rows per lane), reduce in f64 ----
    double s = 0.0;
    s += (double)cost[(size_t)(t * 4 + 0) * N_DIM + c4r0];
    s += (double)cost[(size_t)(t * 4 + 1) * N_DIM + c4r1];
    s += (double)cost[(size_t)(t * 4 + 2) * N_DIM + c4r2];
    s += (double)cost[(size_t)(t * 4 + 3) * N_DIM + c4r3];
    #pragma unroll
    for (int off = 32; off > 0; off >>= 1) s += __shfl_down(s, off);
    if (t == 0) batch_sums[b] = s;
}

__global__ void finalize_kernel(const double* __restrict__ batch_sums,
                                float* __restrict__ out) {
    const int t = threadIdx.x;  // 64 threads, one wave
    double s = batch_sums[t];
    #pragma unroll
    for (int off = 32; off > 0; off >>= 1) s += __shfl_down(s, off);
    if (t == 0) out[0] = (float)(s / (double)((long long)BATCH * N_DIM));
}

extern "C" void kernel_launch(void* const* d_in, const int* in_sizes, int n_in,
                              void* d_out, int out_size, void* d_ws, size_t ws_size,
                              hipStream_t stream) {
    const float* Dm = (const float*)d_in[0];
    float* out = (float*)d_out;
    double* sums = (double*)d_ws;  // 64 * 8 = 512 bytes

    lap_kernel<<<BATCH, BS, 0, stream>>>(Dm, sums);
    finalize_kernel<<<1, 64, 0, stream>>>(sums, out);
}

// Round 13
// 822.888 us; speedup vs baseline: 1.2923x; 1.2010x over previous
//
#include <hip/hip_runtime.h>

#define N_DIM 256
#define BATCH 64
#define BS 64          // one wave per block; lane t owns columns/rows 4t..4t+3
#define SCALE 4096.0f  // fixed-point scale 2^12

#define DPP_MINU(x, ctrl) do {                                                 \
    unsigned _s = (unsigned)__builtin_amdgcn_update_dpp((int)(x), (int)(x),    \
                                                        (ctrl), 0xf, 0xf, false); \
    (x) = ((x) < _s) ? (x) : _s;                                               \
} while (0)

// Hybrid full-wave u32 min: 4 DPP stages reduce within each 16-lane row
// (result in lanes 15/31/47/63), then 4 independent readlanes + scalar mins.
__device__ __forceinline__ unsigned wave_min_u32(unsigned x) {
    DPP_MINU(x, 0x111);  // row_shr:1
    DPP_MINU(x, 0x112);  // row_shr:2
    DPP_MINU(x, 0x114);  // row_shr:4
    DPP_MINU(x, 0x118);  // row_shr:8
    const unsigned a = (unsigned)__builtin_amdgcn_readlane((int)x, 15);
    const unsigned b = (unsigned)__builtin_amdgcn_readlane((int)x, 31);
    const unsigned c = (unsigned)__builtin_amdgcn_readlane((int)x, 47);
    const unsigned d = (unsigned)__builtin_amdgcn_readlane((int)x, 63);
    const unsigned ab = (a < b) ? a : b;
    const unsigned cd = (c < d) ? c : d;
    return (ab < cd) ? ab : cd;
}

// uniform-index lookup from 4 per-lane mirror regs: 2 selects + 1 readlane
__device__ __forceinline__ int rd4_i(int x0, int x1, int x2, int x3, int idx) {
    const int sel = idx & 3, src = idx >> 2;
    int ab = (sel & 1) ? x1 : x0;
    int cd = (sel & 1) ? x3 : x2;
    int vv = (sel & 2) ? cd : ab;
    return __builtin_amdgcn_readlane(vv, src);
}

// owner-lane mirror update (idx wave-uniform)
#define SET4(x0, x1, x2, x3, idx, val) do {                                    \
    const int _sel = (idx) & 3;                                                \
    if (t == ((idx) >> 2)) {                                                   \
        if (_sel == 0) x0 = (val); else if (_sel == 1) x1 = (val);             \
        else if (_sel == 2) x2 = (val); else x3 = (val);                       \
    }                                                                          \
} while (0)

// set scan-guard for column idx on its owner lane
#define SET_GUARD(idx) do {                                                    \
    if (t == ((idx) >> 2)) {                                                   \
        const int _s = (idx) & 3;                                              \
        if (_s == 0) g0 = 0x7FFFFFFF; else if (_s == 1) g1 = 0x7FFFFFFF;       \
        else if (_s == 2) g2 = 0x7FFFFFFF; else g3 = 0x7FFFFFFF;               \
    }                                                                          \
} while (0)

// integer relax of one staged row (hh = packed int2, addv = minVal - u[row])
// scanned cols self-freeze: kn >= k for them since addv >= their spc.
#define RELAX(hh, addv, predrow) do {                                          \
    int r_, kn_;                                                               \
    r_  = (addv) + lo16((hh).x) + vn0;                                         \
    kn_ = (r_ << 8) | c0i; if (kn_ < k0) { p0 = (predrow); k0 = kn_; }         \
    r_  = (addv) + hi16((hh).x) + vn1;                                         \
    kn_ = (r_ << 8) | c1i; if (kn_ < k1) { p1 = (predrow); k1 = kn_; }         \
    r_  = (addv) + lo16((hh).y) + vn2;                                         \
    kn_ = (r_ << 8) | c2i; if (kn_ < k2) { p2 = (predrow); k2 = kn_; }         \
    r_  = (addv) + hi16((hh).y) + vn3;                                         \
    kn_ = (r_ << 8) | c3i; if (kn_ < k3) { p3 = (predrow); k3 = kn_; }         \
} while (0)

__device__ __forceinline__ int lo16(int p) { return (int)(short)(p & 0xFFFF); }
__device__ __forceinline__ int hi16(int p) { return p >> 16; }

// One block = one wave = one batch element.
// JV LAP in i32 FIXED-POINT (scale 2^12) on i16-packed costs staged in LDS:
//   1) column reduction + greedy init
//   2) R8's auction passes (exact bids, eps=0: stalls quickly but its first
//      2-3 passes resolve the cheap conflicts for free; matched edges tight)
//   3) shortest augmenting path (Dijkstra) with DOUBLE-POP SPECULATION:
//      after pop1, the global second-min key (reduce with pop1's guard set;
//      keys unique by col payload) is computed WHILE pop1's row load is in
//      flight, and its row load is issued speculatively. After relax1 a
//      ballot validates that no updated key undercuts key2; if valid, pop2
//      commits in the same iteration (2 pops per latency round). If invalid,
//      the iteration simply ends after relax1 -- the state is exactly the
//      serial single-pop state. Pop sequence identical to serial Dijkstra.
// Result: exact optimum of the quantized matrix. Gather uses ORIGINAL f32.
__global__ __launch_bounds__(BS) void lap_kernel(const float* __restrict__ Dm,
                                                 double* __restrict__ batch_sums) {
    const int b = blockIdx.x;
    const int t = threadIdx.x;  // 0..63
    const float* __restrict__ cost = Dm + (size_t)b * N_DIM * N_DIM;
    const float4* __restrict__ cost4 = (const float4*)cost;

    __shared__ int2     chi[N_DIM * BS];    // [row][lane]: 4 i16 costs, 128 KB
    __shared__ int      u_s[N_DIM];
    __shared__ int      v_s[N_DIM];
    __shared__ int      row4col_s[N_DIM];
    __shared__ int      col4row_s[N_DIM];
    __shared__ int      queue_s[N_DIM];     // doubles as rowcand during greedy
    __shared__ unsigned bid_s[N_DIM];
    __shared__ int      qcnt_s;

    const int c0i = 4 * t, c1i = 4 * t + 1, c2i = 4 * t + 2, c3i = 4 * t + 3;

    // ---- stage i16 matrix + column reduction on QUANTIZED values ----
    int cmn0 = INT_MAX, cmn1 = INT_MAX, cmn2 = INT_MAX, cmn3 = INT_MAX;
    int ca0 = 0, ca1 = 0, ca2 = 0, ca3 = 0;
    for (int r = 0; r < N_DIM; ++r) {
        const float4 c4 = cost4[r * BS + t];
        const int a0 = __float2int_rn(c4.x * SCALE);
        const int a1 = __float2int_rn(c4.y * SCALE);
        const int a2 = __float2int_rn(c4.z * SCALE);
        const int a3 = __float2int_rn(c4.w * SCALE);
        int2 p;
        p.x = (a0 & 0xFFFF) | (a1 << 16);
        p.y = (a2 & 0xFFFF) | (a3 << 16);
        chi[r * BS + t] = p;
        if (a0 < cmn0) { cmn0 = a0; ca0 = r; }
        if (a1 < cmn1) { cmn1 = a1; ca1 = r; }
        if (a2 < cmn2) { cmn2 = a2; ca2 = r; }
        if (a3 < cmn3) { cmn3 = a3; ca3 = r; }
    }
    {
        int4 vv; vv.x = cmn0; vv.y = cmn1; vv.z = cmn2; vv.w = cmn3;
        ((int4*)v_s)[t] = vv;
        int4 zz; zz.x = 0; zz.y = 0; zz.z = 0; zz.w = 0;
        ((int4*)u_s)[t] = zz;
        int4 mm; mm.x = -1; mm.y = -1; mm.z = -1; mm.w = -1;
        ((int4*)row4col_s)[t] = mm;
        ((int4*)col4row_s)[t] = mm;
        int4 rc; rc.x = 0x7fffffff; rc.y = 0x7fffffff; rc.z = 0x7fffffff; rc.w = 0x7fffffff;
        ((int4*)queue_s)[t] = rc;   // rowcand
        uint4 bb; bb.x = ~0u; bb.y = ~0u; bb.z = ~0u; bb.w = ~0u;
        ((uint4*)bid_s)[t] = bb;
    }
    __syncthreads();
    // greedy: each candidate row goes to the lowest claiming column
    atomicMin(&queue_s[ca0], c0i);
    atomicMin(&queue_s[ca1], c1i);
    atomicMin(&queue_s[ca2], c2i);
    atomicMin(&queue_s[ca3], c3i);
    __syncthreads();
    if (queue_s[ca0] == c0i) { row4col_s[c0i] = ca0; col4row_s[ca0] = c0i; }
    if (queue_s[ca1] == c1i) { row4col_s[c1i] = ca1; col4row_s[ca1] = c1i; }
    if (queue_s[ca2] == c2i) { row4col_s[c2i] = ca2; col4row_s[ca2] = c2i; }
    if (queue_s[ca3] == c3i) { row4col_s[c3i] = ca3; col4row_s[ca3] = c3i; }
    __syncthreads();

    // ---- R8 auction passes (exact bids; matched edges stay TIGHT) ----
    for (int pass = 0; pass < 12; ++pass) {
        if (t == 0) qcnt_s = 0;
        __syncthreads();
        {
            const int4 my = ((const int4*)col4row_s)[t];
            const int nf = (my.x < 0) + (my.y < 0) + (my.z < 0) + (my.w < 0);
            if (nf) {
                int pos = atomicAdd(&qcnt_s, nf);
                if (my.x < 0) queue_s[pos++] = c0i;
                if (my.y < 0) queue_s[pos++] = c1i;
                if (my.z < 0) queue_s[pos++] = c2i;
                if (my.w < 0) queue_s[pos++] = c3i;
            }
        }
        __syncthreads();
        const int n = qcnt_s;
        if (n == 0) break;
        for (int base = 0; base < n; base += BS) {
            const int my_row = (base + t < n) ? queue_s[base + t] : -1;
            int d1 = INT_MAX, d2 = INT_MAX;
            int j1 = 0;
            if (my_row >= 0) {
                const int rb = my_row * BS;
                for (int l = 0; l < BS; ++l) {
                    const int l2 = (l + t) & 63;  // rotate start: avoid bank pileup
                    const int2 h = chi[rb + l2];
                    const int4 vv = ((const int4*)v_s)[l2];
                    int d;
                    d = lo16(h.x) - vv.x; if (d < d1) { d2 = d1; d1 = d; j1 = 4 * l2 + 0; } else if (d < d2) d2 = d;
                    d = hi16(h.x) - vv.y; if (d < d1) { d2 = d1; d1 = d; j1 = 4 * l2 + 1; } else if (d < d2) d2 = d;
                    d = lo16(h.y) - vv.z; if (d < d1) { d2 = d1; d1 = d; j1 = 4 * l2 + 2; } else if (d < d2) d2 = d;
                    d = hi16(h.y) - vv.w; if (d < d1) { d2 = d1; d1 = d; j1 = 4 * l2 + 3; } else if (d < d2) d2 = d;
                }
                atomicMin(&bid_s[j1], ((unsigned)d1 << 8) | (unsigned)t);
            }
            __syncthreads();
            if (my_row >= 0) {
                const unsigned mybid = ((unsigned)d1 << 8) | (unsigned)t;
                if (bid_s[j1] == mybid) {  // unique winner per column
                    const int i0 = row4col_s[j1];
                    row4col_s[j1] = my_row;
                    col4row_s[my_row] = j1;
                    if (i0 >= 0) col4row_s[i0] = -1;
                    u_s[my_row] = d2;
                    v_s[j1] += d1 - d2;    // exact: matched edge tight, duals feasible
                    bid_s[j1] = ~0u;       // reset for next round
                }
            }
            __syncthreads();
        }
    }

    // ---- refresh register state from LDS ----
    const int4 vv4 = ((const int4*)v_s)[t];
    int vn0 = -vv4.x, vn1 = -vv4.y, vn2 = -vv4.z, vn3 = -vv4.w;  // negated duals
    const int4 m4 = ((const int4*)row4col_s)[t];
    int r4c0 = m4.x, r4c1 = m4.y, r4c2 = m4.z, r4c3 = m4.w;
    const int4 y4 = ((const int4*)col4row_s)[t];
    int c4r0 = y4.x, c4r1 = y4.y, c4r2 = y4.z, c4r3 = y4.w;
    int p0 = 0, p1 = 0, p2 = 0, p3 = 0;

    unsigned long long fm0 = __ballot(c4r0 < 0);
    unsigned long long fm1 = __ballot(c4r1 < 0);
    unsigned long long fm2 = __ballot(c4r2 < 0);
    unsigned long long fm3 = __ballot(c4r3 < 0);

    const int KINIT0 = (0x7FFFFF << 8) | c0i;
    const int KINIT1 = (0x7FFFFF << 8) | c1i;
    const int KINIT2 = (0x7FFFFF << 8) | c2i;
    const int KINIT3 = (0x7FFFFF << 8) | c3i;

    // ---- shortest augmenting path per remaining free row (double-pop) ----
    while (fm0 | fm1 | fm2 | fm3) {
        int i;
        if (fm0)      { const int tt = __builtin_ctzll(fm0); fm0 &= fm0 - 1; i = tt * 4 + 0; }
        else if (fm1) { const int tt = __builtin_ctzll(fm1); fm1 &= fm1 - 1; i = tt * 4 + 1; }
        else if (fm2) { const int tt = __builtin_ctzll(fm2); fm2 &= fm2 - 1; i = tt * 4 + 2; }
        else          { const int tt = __builtin_ctzll(fm3); fm3 &= fm3 - 1; i = tt * 4 + 3; }

        int k0 = KINIT0, k1 = KINIT1, k2 = KINIT2, k3 = KINIT3;  // (spc<<8)|col
        int g0 = 0, g1 = 0, g2 = 0, g3 = 0;                      // scan guards
        int minVal = 0;
        int sink = -1;

        // prologue: relax the start row (minVal = 0)
        {
            const int2 hS = chi[i * BS + t];
            const int  uS = u_s[i];
            RELAX(hS, -uS, i);
        }

        while (true) {
            // ---- pop1: global min of guarded keys ----
            int q0 = k0 | g0, q1 = k1 | g1, q2 = k2 | g2, q3 = k3 | g3;
            int q01 = (q0 < q1) ? q0 : q1;
            int q23 = (q2 < q3) ? q2 : q3;
            const int gk1 = (int)wave_min_u32((unsigned)((q01 < q23) ? q01 : q23));
            const int bi1 = gk1 & 0xFF;
            SET_GUARD(bi1);
            const int r41 = rd4_i(r4c0, r4c1, r4c2, r4c3, bi1);
            if (r41 < 0) { sink = bi1; minVal = gk1 >> 8; break; }

            // issue pop1's row load NOW; compute second-min while it flies
            const int2 h1 = chi[r41 * BS + t];
            const int  u1 = u_s[r41];

            // ---- pop2 candidate: min with pop1's guard applied ----
            q0 = k0 | g0; q1 = k1 | g1; q2 = k2 | g2; q3 = k3 | g3;
            q01 = (q0 < q1) ? q0 : q1;
            q23 = (q2 < q3) ? q2 : q3;
            const int gk2 = (int)wave_min_u32((unsigned)((q01 < q23) ? q01 : q23));
            const int bi2 = gk2 & 0xFF;
            const int r42 = rd4_i(r4c0, r4c1, r4c2, r4c3, bi2);
            const int rr2 = (r42 < 0) ? 0 : r42;
            const int2 h2 = chi[rr2 * BS + t];   // speculative load
            const int  u2 = u_s[rr2];

            // ---- relax pop1's row ----
            RELAX(h1, (gk1 >> 8) - u1, r41);

            // ---- validate pop2: no updated key may undercut gk2 ----
            const int n0 = k0 | g0, n1 = k1 | g1, n2 = k2 | g2, n3 = k3 | g3;
            const int n01 = (n0 < n1) ? n0 : n1;
            const int n23 = (n2 < n3) ? n2 : n3;
            const int nl  = (n01 < n23) ? n01 : n23;
            if (__ballot((unsigned)nl < (unsigned)gk2) == 0ull) {
                // pop2 commits in the same iteration
                SET_GUARD(bi2);
                if (r42 < 0) { sink = bi2; minVal = gk2 >> 8; break; }
                RELAX(h2, (gk2 >> 8) - u2, r42);
            }
            // invalid: state is exactly the serial post-pop1 state; next
            // iteration re-reduces over the updated keys.
        }

        // dual update (guards mark scanned; matched rows distinct across cols)
        if (g0) { const int dv = minVal - (k0 >> 8); vn0 += dv; if (r4c0 >= 0) u_s[r4c0] += dv; }
        if (g1) { const int dv = minVal - (k1 >> 8); vn1 += dv; if (r4c1 >= 0) u_s[r4c1] += dv; }
        if (g2) { const int dv = minVal - (k2 >> 8); vn2 += dv; if (r4c2 >= 0) u_s[r4c2] += dv; }
        if (g3) { const int dv = minVal - (k3 >> 8); vn3 += dv; if (r4c3 >= 0) u_s[r4c3] += dv; }
        if (t == 0) u_s[i] += minVal;

        // augment alternating path (uniform walk over register mirrors)
        if (sink >= 0) {
            int jj = sink;
            while (true) {
                const int ii = rd4_i(p0, p1, p2, p3, jj);
                SET4(r4c0, r4c1, r4c2, r4c3, jj, ii);
                const int tmp = rd4_i(c4r0, c4r1, c4r2, c4r3, ii);
                SET4(c4r0, c4r1, c4r2, c4r3, ii, jj);
                jj = tmp;
                if (ii == i) break;
            }
        }
    }

    // ---- gather matched ORIGINAL f32 costs (4 rows per lane), reduce in f64 ----
    double s = 0.0;
    s += (double)cost[(size_t)(t * 4 + 0) * N_DIM + c4r0];
    s += (double)cost[(size_t)(t * 4 + 1) * N_DIM + c4r1];
    s += (double)cost[(size_t)(t * 4 + 2) * N_DIM + c4r2];
    s += (double)cost[(size_t)(t * 4 + 3) * N_DIM + c4r3];
    #pragma unroll
    for (int off = 32; off > 0; off >>= 1) s += __shfl_down(s, off);
    if (t == 0) batch_sums[b] = s;
}

__global__ void finalize_kernel(const double* __restrict__ batch_sums,
                                float* __restrict__ out) {
    const int t = threadIdx.x;  // 64 threads, one wave
    double s = batch_sums[t];
    #pragma unroll
    for (int off = 32; off > 0; off >>= 1) s += __shfl_down(s, off);
    if (t == 0) out[0] = (float)(s / (double)((long long)BATCH * N_DIM));
}

extern "C" void kernel_launch(void* const* d_in, const int* in_sizes, int n_in,
                              void* d_out, int out_size, void* d_ws, size_t ws_size,
                              hipStream_t stream) {
    const float* Dm = (const float*)d_in[0];
    float* out = (float*)d_out;
    double* sums = (double*)d_ws;  // 64 * 8 = 512 bytes

    lap_kernel<<<BATCH, BS, 0, stream>>>(Dm, sums);
    finalize_kernel<<<1, 64, 0, stream>>>(sums, out);
}